// Round 9
// baseline (146.037 us; speedup 1.0000x reference)
//
#include <hip/hip_runtime.h>

// FullRelPos: out[b,hw,g, kh*32+kw] = attn[...] + lh[kh] + lw[kw]
//   lh[k] = dot(q[row, 0:32],  rel_emb_h[k-h+31, :])
//   lw[k] = dot(q[row,32:64],  rel_emb_w[k-w+31, :])
//
// Fused, one wave per (b,hw) task (8 g-rows = 32KB stream).
// R8 lessons: nt-stores + CACHED loads is the best memory config (R5=111.4us).
// R5's limiter: VGPR=64 -> 4 waves/SIMD (Occupancy 43%). This round: logits
// go to per-wave LDS instead of 64 hoisted registers (no shfls, no barrier —
// same-wave produce/consume), __launch_bounds__(256,8) pins 8 waves/SIMD.

#define QL 1024    // H*W

typedef float floatx4 __attribute__((ext_vector_type(4)));

__global__ __launch_bounds__(256, 8) void relpos_fused5_kernel(
    const float* __restrict__ q,
    const float* __restrict__ attn,
    const float* __restrict__ reh,
    const float* __restrict__ rew,
    float* __restrict__ out,
    int ntasks)
{
    __shared__ __align__(16) float lgs[4][8][64];   // [wave][g][k], 8 KB

    const int lane = threadIdx.x & 63;
    const int wv   = threadIdx.x >> 6;
    const int wid  = blockIdx.x * 4 + wv;
    const int nwaves = gridDim.x * 4;

    for (int t = wid; t < ntasks; t += nwaves) {
        const int hw = t & (QL - 1);         // task = (b, hw); 8 g-rows per task
        const int h  = hw >> 5;
        const int w  = hw & 31;
        const size_t r0 = (size_t)t << 3;

        // ---- logits: lanes 0..31 own lh[k], lanes 32..63 own lw[k] ----
        const int k = lane & 31;
        const float4* e4 = (lane < 32)
            ? (const float4*)(reh + (size_t)(k - h + 31) * 32)
            : (const float4*)(rew + (size_t)(k - w + 31) * 32);
        const float* qbase = q + r0 * 64 + (lane & 32);

        float acc[8];
        #pragma unroll
        for (int g = 0; g < 8; ++g) acc[g] = 0.f;
        #pragma unroll
        for (int c4 = 0; c4 < 8; ++c4) {
            const float4 ev = e4[c4];
            #pragma unroll
            for (int g = 0; g < 8; ++g) {
                const float4 qv = *(const float4*)(qbase + g * 64 + c4 * 4);
                acc[g] += qv.x * ev.x + qv.y * ev.y + qv.z * ev.z + qv.w * ev.w;
            }
        }

        // ---- park logits in LDS (same-wave consume; no barrier needed) ----
        #pragma unroll
        for (int g = 0; g < 8; ++g)
            lgs[wv][g][lane] = acc[g];

        // lane's float4 unit u = lane + 64*j: kh = (lane>>3) + 8j, kw0 = (4*lane)&31
        const int kw0 = (lane << 2) & 31;
        const int kh0 = lane >> 3;

        // ---- stream: cached loads, 2-deep dbuf, nt stores; logits from LDS ----
        const float4*  abase = (const float4*)(attn + r0 * QL);
        floatx4*       obase = (floatx4*)(out  + r0 * QL);

        float4 buf[2][4];
        #pragma unroll
        for (int j = 0; j < 4; ++j)
            buf[0][j] = abase[lane + 64 * j];

        #pragma unroll
        for (int g = 0; g < 8; ++g) {
            if (g < 7) {
                const float4* anext = abase + (size_t)(g + 1) * 256;
                #pragma unroll
                for (int j = 0; j < 4; ++j)
                    buf[(g + 1) & 1][j] = anext[lane + 64 * j];
            }
            const float* lrow = &lgs[wv][g][0];
            const float4 lw4  = *(const float4*)(lrow + 32 + kw0);
            float lhv[4];
            #pragma unroll
            for (int j = 0; j < 4; ++j)
                lhv[j] = lrow[kh0 + 8 * j];

            floatx4* orow = obase + (size_t)g * 256;
            #pragma unroll
            for (int j = 0; j < 4; ++j) {
                const float4 a = buf[g & 1][j];
                const float tl = lhv[j];
                floatx4 o;
                o.x = a.x + tl + lw4.x;
                o.y = a.y + tl + lw4.y;
                o.z = a.z + tl + lw4.z;
                o.w = a.w + tl + lw4.w;
                __builtin_nontemporal_store(o, &orow[lane + 64 * j]);
            }
        }
    }
}

extern "C" void kernel_launch(void* const* d_in, const int* in_sizes, int n_in,
                              void* d_out, int out_size, void* d_ws, size_t ws_size,
                              hipStream_t stream) {
    const float* q    = (const float*)d_in[0];
    const float* attn = (const float*)d_in[1];
    const float* reh  = (const float*)d_in[2];
    const float* rew  = (const float*)d_in[3];
    float* out = (float*)d_out;

    const int nrows  = in_sizes[1] / QL;   // B * QL * G = 65536
    const int ntasks = nrows >> 3;         // 8192 -> one per wave
    relpos_fused5_kernel<<<2048, 256, 0, stream>>>(q, attn, reh, rew, out, ntasks);
}

// Round 10
// 101.031 us; speedup vs baseline: 1.4455x; 1.4455x over previous
//
#include <hip/hip_runtime.h>

// FullRelPos: out[b,hw,g, kh*32+kw] = attn[...] + lh[kh] + lw[kw]
//   lh[k] = dot(q[row, 0:32],  rel_emb_h[k-h+31, :])
//   lw[k] = dot(q[row,32:64],  rel_emb_w[k-w+31, :])
//
// Fused, one wave per (b,hw) task (8 g-rows = 32KB stream).
// Cache-policy 2x2: cached+nt=111.4 (R5), plain+plain=128.8 (R7),
// nt+nt=115.2 (R8). This round: NT LOADS + PLAIN STORES — reads don't
// allocate (no L2/L3 fight), writes get the full cache write-back path
// (fill proves plain stores do 7 TB/s).

#define QL 1024    // H*W

typedef float floatx4 __attribute__((ext_vector_type(4)));

__global__ __launch_bounds__(256) void relpos_fused6_kernel(
    const float* __restrict__ q,
    const float* __restrict__ attn,
    const float* __restrict__ reh,
    const float* __restrict__ rew,
    float* __restrict__ out,
    int ntasks)
{
    const int lane = threadIdx.x & 63;
    const int wid  = blockIdx.x * 4 + (threadIdx.x >> 6);
    const int nwaves = gridDim.x * 4;

    for (int t = wid; t < ntasks; t += nwaves) {
        const int hw = t & (QL - 1);         // task = (b, hw); 8 g-rows per task
        const int h  = hw >> 5;
        const int w  = hw & 31;
        const size_t r0 = (size_t)t << 3;

        // ---- logits: lanes 0..31 own lh[k], lanes 32..63 own lw[k] ----
        const int k = lane & 31;
        const float4* e4 = (lane < 32)
            ? (const float4*)(reh + (size_t)(k - h + 31) * 32)
            : (const float4*)(rew + (size_t)(k - w + 31) * 32);
        const float* qbase = q + r0 * 64 + (lane & 32);

        float acc[8];
        #pragma unroll
        for (int g = 0; g < 8; ++g) acc[g] = 0.f;
        #pragma unroll
        for (int c4 = 0; c4 < 8; ++c4) {
            const float4 ev = e4[c4];
            #pragma unroll
            for (int g = 0; g < 8; ++g) {
                const float4 qv = *(const float4*)(qbase + g * 64 + c4 * 4);
                acc[g] += qv.x * ev.x + qv.y * ev.y + qv.z * ev.z + qv.w * ev.w;
            }
        }

        // ---- redistribute ALL logits up front (no shfls in the stream loop) ----
        // lane's float4 unit u = lane + 64*j: kh = lane/8 + 8j, kw0 = (4*lane)&31
        const int kw0 = (lane << 2) & 31;
        const int kh0 = lane >> 3;
        float lh[8][4], lw[8][4];
        #pragma unroll
        for (int g = 0; g < 8; ++g) {
            const float a = acc[g];
            lh[g][0] = __shfl(a, kh0,      64);
            lh[g][1] = __shfl(a, kh0 + 8,  64);
            lh[g][2] = __shfl(a, kh0 + 16, 64);
            lh[g][3] = __shfl(a, kh0 + 24, 64);
            lw[g][0] = __shfl(a, 32 + kw0,     64);
            lw[g][1] = __shfl(a, 32 + kw0 + 1, 64);
            lw[g][2] = __shfl(a, 32 + kw0 + 2, 64);
            lw[g][3] = __shfl(a, 32 + kw0 + 3, 64);
        }

        // ---- stream: NT loads, 2-deep dbuf, PLAIN stores ----
        const floatx4* abase = (const floatx4*)(attn + r0 * QL);
        float4*        obase = (float4*)(out  + r0 * QL);

        floatx4 buf[2][4];
        #pragma unroll
        for (int j = 0; j < 4; ++j)
            buf[0][j] = __builtin_nontemporal_load(abase + lane + 64 * j);

        #pragma unroll
        for (int g = 0; g < 8; ++g) {
            if (g < 7) {
                const floatx4* anext = abase + (size_t)(g + 1) * 256;
                #pragma unroll
                for (int j = 0; j < 4; ++j)
                    buf[(g + 1) & 1][j] =
                        __builtin_nontemporal_load(anext + lane + 64 * j);
            }
            float4* orow = obase + (size_t)g * 256;
            #pragma unroll
            for (int j = 0; j < 4; ++j) {
                const floatx4 a = buf[g & 1][j];
                const float tl = lh[g][j];
                float4 o;
                o.x = a.x + tl + lw[g][0];
                o.y = a.y + tl + lw[g][1];
                o.z = a.z + tl + lw[g][2];
                o.w = a.w + tl + lw[g][3];
                orow[lane + 64 * j] = o;
            }
        }
    }
}

extern "C" void kernel_launch(void* const* d_in, const int* in_sizes, int n_in,
                              void* d_out, int out_size, void* d_ws, size_t ws_size,
                              hipStream_t stream) {
    const float* q    = (const float*)d_in[0];
    const float* attn = (const float*)d_in[1];
    const float* reh  = (const float*)d_in[2];
    const float* rew  = (const float*)d_in[3];
    float* out = (float*)d_out;

    const int nrows  = in_sizes[1] / QL;   // B * QL * G = 65536
    const int ntasks = nrows >> 3;         // 8192 -> one per wave
    relpos_fused6_kernel<<<2048, 256, 0, stream>>>(q, attn, reh, rew, out, ntasks);
}

// Round 11
// 99.697 us; speedup vs baseline: 1.4648x; 1.0134x over previous
//
#include <hip/hip_runtime.h>

// FullRelPos: out[b,hw,g, kh*32+kw] = attn[...] + lh[kh] + lw[kw]
//   lh[k] = dot(q[row, 0:32],  rel_emb_h[k-h+31, :])
//   lw[k] = dot(q[row,32:64],  rel_emb_w[k-w+31, :])
//
// Fused, one wave per (b,hw) task (8 g-rows = 32KB stream).
// Cache-policy matrix settled: NT loads + PLAIN stores wins (101.0 us vs
// 111.4/115.2/128.8). This round: hoist the g=0 attn loads ABOVE the
// logits prologue so first-row HBM latency hides under the dot/shfl compute.

#define QL 1024    // H*W

typedef float floatx4 __attribute__((ext_vector_type(4)));

__global__ __launch_bounds__(256) void relpos_fused7_kernel(
    const float* __restrict__ q,
    const float* __restrict__ attn,
    const float* __restrict__ reh,
    const float* __restrict__ rew,
    float* __restrict__ out,
    int ntasks)
{
    const int lane = threadIdx.x & 63;
    const int wid  = blockIdx.x * 4 + (threadIdx.x >> 6);
    const int nwaves = gridDim.x * 4;

    for (int t = wid; t < ntasks; t += nwaves) {
        const int hw = t & (QL - 1);         // task = (b, hw); 8 g-rows per task
        const int h  = hw >> 5;
        const int w  = hw & 31;
        const size_t r0 = (size_t)t << 3;

        // ---- issue g=0 attn loads FIRST (latency hides under prologue) ----
        const floatx4* abase = (const floatx4*)(attn + r0 * QL);
        floatx4 buf[2][4];
        #pragma unroll
        for (int j = 0; j < 4; ++j)
            buf[0][j] = __builtin_nontemporal_load(abase + lane + 64 * j);

        // ---- logits: lanes 0..31 own lh[k], lanes 32..63 own lw[k] ----
        const int k = lane & 31;
        const float4* e4 = (lane < 32)
            ? (const float4*)(reh + (size_t)(k - h + 31) * 32)
            : (const float4*)(rew + (size_t)(k - w + 31) * 32);
        const float* qbase = q + r0 * 64 + (lane & 32);

        float acc[8];
        #pragma unroll
        for (int g = 0; g < 8; ++g) acc[g] = 0.f;
        #pragma unroll
        for (int c4 = 0; c4 < 8; ++c4) {
            const float4 ev = e4[c4];
            #pragma unroll
            for (int g = 0; g < 8; ++g) {
                const float4 qv = *(const float4*)(qbase + g * 64 + c4 * 4);
                acc[g] += qv.x * ev.x + qv.y * ev.y + qv.z * ev.z + qv.w * ev.w;
            }
        }

        // ---- redistribute ALL logits up front (no shfls in the stream loop) ----
        // lane's float4 unit u = lane + 64*j: kh = lane/8 + 8j, kw0 = (4*lane)&31
        const int kw0 = (lane << 2) & 31;
        const int kh0 = lane >> 3;
        float lh[8][4], lw[8][4];
        #pragma unroll
        for (int g = 0; g < 8; ++g) {
            const float a = acc[g];
            lh[g][0] = __shfl(a, kh0,      64);
            lh[g][1] = __shfl(a, kh0 + 8,  64);
            lh[g][2] = __shfl(a, kh0 + 16, 64);
            lh[g][3] = __shfl(a, kh0 + 24, 64);
            lw[g][0] = __shfl(a, 32 + kw0,     64);
            lw[g][1] = __shfl(a, 32 + kw0 + 1, 64);
            lw[g][2] = __shfl(a, 32 + kw0 + 2, 64);
            lw[g][3] = __shfl(a, 32 + kw0 + 3, 64);
        }

        // ---- stream: NT loads, 2-deep dbuf, PLAIN stores ----
        float4* obase = (float4*)(out + r0 * QL);

        #pragma unroll
        for (int g = 0; g < 8; ++g) {
            if (g < 7) {
                const floatx4* anext = abase + (size_t)(g + 1) * 256;
                #pragma unroll
                for (int j = 0; j < 4; ++j)
                    buf[(g + 1) & 1][j] =
                        __builtin_nontemporal_load(anext + lane + 64 * j);
            }
            float4* orow = obase + (size_t)g * 256;
            #pragma unroll
            for (int j = 0; j < 4; ++j) {
                const floatx4 a = buf[g & 1][j];
                const float tl = lh[g][j];
                float4 o;
                o.x = a.x + tl + lw[g][0];
                o.y = a.y + tl + lw[g][1];
                o.z = a.z + tl + lw[g][2];
                o.w = a.w + tl + lw[g][3];
                orow[lane + 64 * j] = o;
            }
        }
    }
}

extern "C" void kernel_launch(void* const* d_in, const int* in_sizes, int n_in,
                              void* d_out, int out_size, void* d_ws, size_t ws_size,
                              hipStream_t stream) {
    const float* q    = (const float*)d_in[0];
    const float* attn = (const float*)d_in[1];
    const float* reh  = (const float*)d_in[2];
    const float* rew  = (const float*)d_in[3];
    float* out = (float*)d_out;

    const int nrows  = in_sizes[1] / QL;   // B * QL * G = 65536
    const int ntasks = nrows >> 3;         // 8192 -> one per wave
    relpos_fused7_kernel<<<2048, 256, 0, stream>>>(q, attn, reh, rew, out, ntasks);
}